// Round 1
// baseline (1438.522 us; speedup 1.0000x reference)
//
#include <hip/hip_runtime.h>
#include <hip/hip_bf16.h>

#define N_    32
#define CIN_  64
#define COUT_ 64
#define T_    1024
#define V_    25
#define K_    3
#define KC_   192      // K_*COUT_
#define TT_   16       // t-values per block
#define VP_   28       // padded row stride (112 B, 16B-aligned)
#define WTP_  196      // padded kc stride for transposed W (breaks bank conflicts)
#define EPSV  1e-5f

// workspace layout (float offsets) — total < 16 KB
#define WS_AF    0      // Afull padded [3][25][28] = 2100
#define WS_BIAS2 2112   // bias2 [64][25] = 1600
#define WS_SUM   3712   // per-channel sum [64]
#define WS_SQ    3776   // per-channel sumsq [64]
#define WS_SCALE 3840   // gamma*rsigma [64]
#define WS_SHIFT 3904   // beta - mu*scale [64]

__device__ __forceinline__ float bf16u_to_f(unsigned short u) {
    return __uint_as_float(((unsigned int)u) << 16);
}
__device__ __forceinline__ unsigned short f_to_bf16u(float f) {
    unsigned int b = __float_as_uint(f);
    b += 0x7fffu + ((b >> 16) & 1u);   // round-to-nearest-even
    return (unsigned short)(b >> 16);
}

// acc[0..24] += m * row[0..24]; row is 16B-aligned LDS
__device__ __forceinline__ void fma_row25(float m, const float* __restrict__ row,
                                          float* __restrict__ acc) {
    const float4* r4 = (const float4*)row;
    float4 a = r4[0], b = r4[1], c = r4[2], d = r4[3], e = r4[4], f = r4[5];
    float g = row[24];
    acc[0]  = fmaf(m, a.x, acc[0]);   acc[1]  = fmaf(m, a.y, acc[1]);
    acc[2]  = fmaf(m, a.z, acc[2]);   acc[3]  = fmaf(m, a.w, acc[3]);
    acc[4]  = fmaf(m, b.x, acc[4]);   acc[5]  = fmaf(m, b.y, acc[5]);
    acc[6]  = fmaf(m, b.z, acc[6]);   acc[7]  = fmaf(m, b.w, acc[7]);
    acc[8]  = fmaf(m, c.x, acc[8]);   acc[9]  = fmaf(m, c.y, acc[9]);
    acc[10] = fmaf(m, c.z, acc[10]);  acc[11] = fmaf(m, c.w, acc[11]);
    acc[12] = fmaf(m, d.x, acc[12]);  acc[13] = fmaf(m, d.y, acc[13]);
    acc[14] = fmaf(m, d.z, acc[14]);  acc[15] = fmaf(m, d.w, acc[15]);
    acc[16] = fmaf(m, e.x, acc[16]);  acc[17] = fmaf(m, e.y, acc[17]);
    acc[18] = fmaf(m, e.z, acc[18]);  acc[19] = fmaf(m, e.w, acc[19]);
    acc[20] = fmaf(m, f.x, acc[20]);  acc[21] = fmaf(m, f.y, acc[21]);
    acc[22] = fmaf(m, f.z, acc[22]);  acc[23] = fmaf(m, f.w, acc[23]);
    acc[24] = fmaf(m, g, acc[24]);
}

// ---------------- kernel 0: Afull = A+PA (padded), bias2, zero sums ----------
__global__ void gcn_prep(const float* __restrict__ A, const float* __restrict__ PA,
                         const float* __restrict__ b, float* ws) {
    __shared__ float cs[K_ * V_];   // column sums of Afull: cs[k*25+w] = sum_v Afull[k][v][w]
    int tid = threadIdx.x;
    if (tid < K_ * V_) {
        int k = tid / V_, w = tid % V_;
        float s = 0.f;
        for (int v = 0; v < V_; ++v) {
            int idx = (k * V_ + v) * V_ + w;
            s += A[idx] + PA[idx];
        }
        cs[tid] = s;
    }
    for (int f = tid; f < K_ * V_ * VP_; f += blockDim.x) {
        int k = f / (V_ * VP_);
        int r = f % (V_ * VP_);
        int v = r / VP_;
        int w = r % VP_;
        float val = 0.f;
        if (w < V_) {
            int idx = (k * V_ + v) * V_ + w;
            val = A[idx] + PA[idx];
        }
        ws[WS_AF + f] = val;
    }
    if (tid < 2 * COUT_) ws[WS_SUM + tid] = 0.f;   // SUM and SQ are contiguous
    __syncthreads();
    for (int f = tid; f < COUT_ * V_; f += blockDim.x) {
        int c = f / V_, w = f % V_;
        float s = 0.f;
        for (int k = 0; k < K_; ++k) s += b[k * COUT_ + c] * cs[k * V_ + w];
        ws[WS_BIAS2 + f] = s;
    }
}

// ---------------- kernel 1: fused conv + graph-agg, agg -> d_out, partial stats
// block = 192 threads = 3 waves; thread kc in [0,192); k = kc>>6 is wave-uniform.
__global__ __launch_bounds__(192, 2)
void gcn_main(const float* __restrict__ x, const float* __restrict__ W,
              float* ws, float* __restrict__ out) {
    __shared__ __align__(16) unsigned short wt[CIN_][WTP_];  // W^T, bf16 (24.5 KB)
    __shared__ __align__(16) float af[K_][V_][VP_];          // Afull (8.4 KB)
    __shared__ __align__(16) float xs[2][CIN_][VP_];         // x slices, 2 t's (14.3 KB)
    __shared__ __align__(16) float pbuf[2][2][COUT_][26];    // k=1,2 partials (26.6 KB)

    const int tid = threadIdx.x;
    const int bid = blockIdx.x;
    const int n  = bid >> 6;           // T_/TT_ = 64 chunks
    const int t0 = (bid & 63) * TT_;

    // stage W^T into LDS as bf16 (coalesced global read; WTP_=196 pad -> ~4-way write conflicts only)
    for (int f = tid; f < KC_ * CIN_; f += 192) {
        int kc = f >> 6;
        int ci = f & 63;
        wt[ci][kc] = f_to_bf16u(W[f]);
    }
    // stage Afull (pre-padded in ws)
    for (int f = tid; f < K_ * V_ * VP_; f += 192) {
        ((float*)af)[f] = ws[WS_AF + f];
    }

    const int kc = tid;
    const int k  = kc >> 6;
    const int c  = kc & 63;

    float bias_r[V_];
    if (k == 0) {
        #pragma unroll
        for (int w = 0; w < V_; ++w) bias_r[w] = ws[WS_BIAS2 + kc * V_ + w];
    }

    float lsum = 0.f, lsq = 0.f;

    for (int pi = 0; pi < TT_ / 2; ++pi) {
        const int t = t0 + 2 * pi;
        // cooperative x load: 2 t-slices, 64 channels x 25 joints each
        for (int f = tid; f < 2 * CIN_ * V_; f += 192) {
            int tt = f / (CIN_ * V_);
            int r  = f % (CIN_ * V_);
            int ci = r / V_;
            int v  = r % V_;
            xs[tt][ci][v] = x[(((size_t)n * CIN_ + ci) * T_ + (t + tt)) * V_ + v];
        }
        __syncthreads();

        // stage 1: y[tt][v] = sum_ci W[kc][ci] * x[ci][v]  (x reads broadcast across lanes)
        float y[2][V_];
        #pragma unroll
        for (int v = 0; v < V_; ++v) { y[0][v] = 0.f; y[1][v] = 0.f; }
        #pragma unroll 4
        for (int ci = 0; ci < CIN_; ++ci) {
            float wv = bf16u_to_f(wt[ci][kc]);
            fma_row25(wv, &xs[0][ci][0], &y[0][0]);
            fma_row25(wv, &xs[1][ci][0], &y[1][0]);
        }

        // stage 2: p[tt][w] = sum_v y[tt][v] * Afull[k][v][w]  (Af reads wave-uniform broadcast)
        float p[2][V_];
        #pragma unroll
        for (int v = 0; v < V_; ++v) { p[0][v] = 0.f; p[1][v] = 0.f; }
        #pragma unroll 5
        for (int v = 0; v < V_; ++v) {
            const float* ar = &af[k][v][0];
            fma_row25(y[0][v], ar, &p[0][0]);
            fma_row25(y[1][v], ar, &p[1][0]);
        }

        if (k > 0) {
            #pragma unroll
            for (int w = 0; w < V_; ++w) {
                pbuf[0][k - 1][c][w] = p[0][w];
                pbuf[1][k - 1][c][w] = p[1][w];
            }
        }
        __syncthreads();

        if (k == 0) {
            #pragma unroll
            for (int tt = 0; tt < 2; ++tt) {
                size_t base = (((size_t)n * COUT_ + c) * T_ + (t + tt)) * (size_t)V_;
                #pragma unroll
                for (int w = 0; w < V_; ++w) {
                    float a = p[tt][w] + pbuf[tt][0][c][w] + pbuf[tt][1][c][w] + bias_r[w];
                    lsum += a;
                    lsq  = fmaf(a, a, lsq);
                    out[base + w] = a;
                }
            }
        }
        // next iter: xs overwrite is safe (all stage-1/2 reads done before 2nd barrier);
        // pbuf overwrite waits behind the next 1st barrier, which wave0 reaches after epilogue.
    }

    if (k == 0) {
        atomicAdd(&ws[WS_SUM + c], lsum);
        atomicAdd(&ws[WS_SQ  + c], lsq);
    }
}

// ---------------- kernel 2: finalize BN stats ------------------------------
__global__ void gcn_stats(float* ws, const float* __restrict__ gamma,
                          const float* __restrict__ beta) {
    int c = threadIdx.x;
    if (c < COUT_) {
        const float cnt = (float)(N_ * T_ * V_);   // 819200
        float mu  = ws[WS_SUM + c] / cnt;
        float var = ws[WS_SQ + c] / cnt - mu * mu;
        float rs  = rsqrtf(var + EPSV);
        float sc  = gamma[c] * rs;
        ws[WS_SCALE + c] = sc;
        ws[WS_SHIFT + c] = fmaf(-mu, sc, beta[c]);
    }
}

// ---------------- kernel 3: BN apply + residual + ReLU (in-place on d_out) --
__global__ __launch_bounds__(256)
void gcn_finish(const float* __restrict__ x, const float* ws, float* out) {
    const int total4 = N_ * COUT_ * T_ * V_ / 4;   // 13107200; c-period (25600) % 4 == 0
    int stride = gridDim.x * blockDim.x;
    for (int i = blockIdx.x * blockDim.x + threadIdx.x; i < total4; i += stride) {
        int c = (i / 6400) & 63;                    // (4i / 25600) % 64
        float sc = ws[WS_SCALE + c];
        float sh = ws[WS_SHIFT + c];
        float4 a  = ((const float4*)out)[i];
        float4 xv = ((const float4*)x)[i];
        a.x = fmaxf(0.f, fmaf(a.x, sc, sh) + xv.x);
        a.y = fmaxf(0.f, fmaf(a.y, sc, sh) + xv.y);
        a.z = fmaxf(0.f, fmaf(a.z, sc, sh) + xv.z);
        a.w = fmaxf(0.f, fmaf(a.w, sc, sh) + xv.w);
        ((float4*)out)[i] = a;
    }
}

extern "C" void kernel_launch(void* const* d_in, const int* in_sizes, int n_in,
                              void* d_out, int out_size, void* d_ws, size_t ws_size,
                              hipStream_t stream) {
    (void)in_sizes; (void)n_in; (void)out_size; (void)ws_size;
    const float* x     = (const float*)d_in[0];
    const float* W     = (const float*)d_in[1];
    const float* b     = (const float*)d_in[2];
    const float* A     = (const float*)d_in[3];
    const float* PA    = (const float*)d_in[4];
    const float* gamma = (const float*)d_in[5];
    const float* beta  = (const float*)d_in[6];
    float* out = (float*)d_out;
    float* ws  = (float*)d_ws;

    gcn_prep<<<1, 256, 0, stream>>>(A, PA, b, ws);
    gcn_main<<<N_ * (T_ / TT_), 192, 0, stream>>>(x, W, ws, out);
    gcn_stats<<<1, 64, 0, stream>>>(ws, gamma, beta);
    gcn_finish<<<4096, 256, 0, stream>>>(x, ws, out);
}

// Round 2
// 846.265 us; speedup vs baseline: 1.6998x; 1.6998x over previous
//
#include <hip/hip_runtime.h>
#include <hip/hip_bf16.h>

#define N_    32
#define CIN_  64
#define COUT_ 64
#define T_    1024
#define V_    25
#define K_    3
#define TC_   4        // t-values per gcn_main block
#define EPSV  1e-5f

// ws float offsets
#define WS_AF     0        // Afull padded [3][25][28] = 2100
#define WS_BIAS2  2112     // [64 c][25 w] = 1600
#define WS_WPK    3712     // packed bf16 W pairs, [32 j][192 kc] (uint) = 6144
#define WS_SUM    9856     // [8 slot][64 c]
#define WS_SQ     10368    // [8 slot][64 c]
#define WS_SCALE  10880    // [64]
#define WS_SHIFT  10944    // [64]

__device__ __forceinline__ unsigned short f_to_bf16u(float f) {
    unsigned int b = __float_as_uint(f);
    b += 0x7fffu + ((b >> 16) & 1u);   // RNE
    return (unsigned short)(b >> 16);
}

// acc[0..24] += m * row[0..24]; row is 16B-aligned LDS
__device__ __forceinline__ void fma_row25(float m, const float* __restrict__ row,
                                          float* __restrict__ acc) {
    const float4* r4 = (const float4*)row;
    float4 a = r4[0], b = r4[1], c = r4[2], d = r4[3], e = r4[4], f = r4[5];
    float g = row[24];
    acc[0]  = fmaf(m, a.x, acc[0]);   acc[1]  = fmaf(m, a.y, acc[1]);
    acc[2]  = fmaf(m, a.z, acc[2]);   acc[3]  = fmaf(m, a.w, acc[3]);
    acc[4]  = fmaf(m, b.x, acc[4]);   acc[5]  = fmaf(m, b.y, acc[5]);
    acc[6]  = fmaf(m, b.z, acc[6]);   acc[7]  = fmaf(m, b.w, acc[7]);
    acc[8]  = fmaf(m, c.x, acc[8]);   acc[9]  = fmaf(m, c.y, acc[9]);
    acc[10] = fmaf(m, c.z, acc[10]);  acc[11] = fmaf(m, c.w, acc[11]);
    acc[12] = fmaf(m, d.x, acc[12]);  acc[13] = fmaf(m, d.y, acc[13]);
    acc[14] = fmaf(m, d.z, acc[14]);  acc[15] = fmaf(m, d.w, acc[15]);
    acc[16] = fmaf(m, e.x, acc[16]);  acc[17] = fmaf(m, e.y, acc[17]);
    acc[18] = fmaf(m, e.z, acc[18]);  acc[19] = fmaf(m, e.w, acc[19]);
    acc[20] = fmaf(m, f.x, acc[20]);  acc[21] = fmaf(m, f.y, acc[21]);
    acc[22] = fmaf(m, f.z, acc[22]);  acc[23] = fmaf(m, f.w, acc[23]);
    acc[24] = fmaf(m, g, acc[24]);
}

// ---- kernel 0: Afull (padded), bias2, packed-bf16 W, zero stat slots -------
__global__ void gcn_prep(const float* __restrict__ A, const float* __restrict__ PA,
                         const float* __restrict__ b, const float* __restrict__ W,
                         float* ws) {
    __shared__ float cs[K_ * V_];   // column sums of Afull
    int tid = threadIdx.x;
    if (tid < K_ * V_) {
        int k = tid / V_, w = tid % V_;
        float s = 0.f;
        for (int v = 0; v < V_; ++v) {
            int idx = (k * V_ + v) * V_ + w;
            s += A[idx] + PA[idx];
        }
        cs[tid] = s;
    }
    // Afull padded [3][25][28]
    for (int f = tid; f < K_ * V_ * 28; f += blockDim.x) {
        int k = f / (V_ * 28);
        int r = f % (V_ * 28);
        int v = r / 28;
        int w = r % 28;
        float val = 0.f;
        if (w < V_) {
            int idx = (k * V_ + v) * V_ + w;
            val = A[idx] + PA[idx];
        }
        ws[WS_AF + f] = val;
    }
    // zero the 8 atomic stat slots (SUM+SQ contiguous: 1024 floats)
    for (int f = tid; f < 1024; f += blockDim.x) ws[WS_SUM + f] = 0.f;
    // packed W: wpk[j*192 + kc] = bf16(W[kc][2j]) | bf16(W[kc][2j+1])<<16
    unsigned int* wpk = (unsigned int*)(ws + WS_WPK);
    for (int f = tid; f < 32 * 192; f += blockDim.x) {
        int j = f / 192, kc = f % 192;
        unsigned int lo = f_to_bf16u(W[kc * CIN_ + 2 * j]);
        unsigned int hi = f_to_bf16u(W[kc * CIN_ + 2 * j + 1]);
        wpk[f] = lo | (hi << 16);
    }
    __syncthreads();
    // bias2[c][w] = sum_k b[k*64+c] * colsum[k][w]
    for (int f = tid; f < COUT_ * V_; f += blockDim.x) {
        int c = f / V_, w = f % V_;
        float s = 0.f;
        for (int k = 0; k < K_; ++k) s += b[k * COUT_ + c] * cs[k * V_ + w];
        ws[WS_BIAS2 + f] = s;
    }
}

// ---- kernel 1: fused conv + agg; agg -> d_out; per-block stat atomics ------
// block = 256 = 64 c x 4 t; grid = 32 n x 256 t-chunks = 8192
__global__ __launch_bounds__(256, 4)
void gcn_main(const float* __restrict__ x, float* __restrict__ ws,
              float* __restrict__ out) {
    // union: compute phase = xs[4][64][28] (7168) + af[3][25][28] (2100)
    //        epilogue      = ostage[64][101] (6464)  -- overlaps xs
    __shared__ __align__(16) float smem[TC_ * CIN_ * 28 + 2100];
    __shared__ __align__(16) float sstat[4 * 64 * 2];

    float* xs = smem;                    // [tt][ci][28]
    float* af = smem + TC_ * CIN_ * 28;  // [k][v][28]
    float* ostage = smem;                // [c][101]

    const int tid = threadIdx.x;
    const int bid = blockIdx.x;
    const int n  = bid >> 8;
    const int tc = bid & 255;
    const int c  = tid & 63;
    const int tg = tid >> 6;

    // ---- stage x (coalesced float4 reads, scalar LDS writes) ----
    const float4* xg = (const float4*)x;
    for (int f = tid; f < CIN_ * 25; f += 256) {
        int ci = f / 25;
        int j  = f - ci * 25;
        float4 g = xg[((size_t)(n * CIN_ + ci)) * 6400 + tc * 25 + j];
        int flat = 4 * j;
        int tt = flat / 25;
        int v  = flat - tt * 25;
        float vals[4] = {g.x, g.y, g.z, g.w};
        #pragma unroll
        for (int e = 0; e < 4; ++e) {
            xs[(tt * CIN_ + ci) * 28 + v] = vals[e];
            if (++v == 25) { v = 0; ++tt; }
        }
    }
    // ---- stage Afull ----
    for (int f = tid; f < 2100; f += 256) af[f] = ws[WS_AF + f];
    __syncthreads();

    // ---- compute: thread owns (c, t = t0+tg); full k-sum in registers ----
    const unsigned int* wpk = (const unsigned int*)(ws + WS_WPK);
    const float* xrow_base = xs + (tg * CIN_) * 28;

    float p[25];
    #pragma unroll
    for (int w = 0; w < 25; ++w) p[w] = ws[WS_BIAS2 + c * 25 + w];

    for (int k = 0; k < K_; ++k) {
        float y[25];
        #pragma unroll
        for (int v = 0; v < 25; ++v) y[v] = 0.f;
        const unsigned int* wrow = wpk + k * 64 + c;   // +192 per j
        #pragma unroll 1
        for (int jb = 0; jb < 4; ++jb) {
            unsigned int w8[8];
            #pragma unroll
            for (int jj = 0; jj < 8; ++jj) w8[jj] = wrow[(jb * 8 + jj) * 192];
            #pragma unroll
            for (int jj = 0; jj < 8; ++jj) {
                float w0 = __uint_as_float(w8[jj] << 16);
                float w1 = __uint_as_float(w8[jj] & 0xffff0000u);
                int ci = 2 * (jb * 8 + jj);
                fma_row25(w0, xrow_base + ci * 28, y);
                fma_row25(w1, xrow_base + (ci + 1) * 28, y);
            }
        }
        const float* afk = af + k * V_ * 28;
        #pragma unroll 5
        for (int v = 0; v < 25; ++v)
            fma_row25(y[v], afk + v * 28, p);
    }

    // per-thread stats (c fixed for this thread)
    float lsum = 0.f, lsq = 0.f;
    #pragma unroll
    for (int w = 0; w < 25; ++w) { lsum += p[w]; lsq = fmaf(p[w], p[w], lsq); }

    __syncthreads();   // xs/af reads complete before ostage overwrite

    #pragma unroll
    for (int w = 0; w < 25; ++w) ostage[c * 101 + tg * 25 + w] = p[w];
    sstat[(tg * 64 + c) * 2]     = lsum;
    sstat[(tg * 64 + c) * 2 + 1] = lsq;
    __syncthreads();

    // ---- coalesced global write: 6400 floats = 64 c x (4t*25v) ----
    const size_t obase = ((size_t)(n * COUT_)) * 25600 + tc * 100;
    #pragma unroll 1
    for (int it = 0; it < 25; ++it) {
        int idx = it * 256 + tid;
        int cc = idx / 100;
        int r  = idx - cc * 100;
        out[obase + (size_t)cc * 25600 + r] = ostage[cc * 101 + r];
    }

    // ---- stats reduce (4 partials per c) + slotted atomics ----
    if (tg == 0) {
        float s = sstat[c * 2] + sstat[(64 + c) * 2] + sstat[(128 + c) * 2] + sstat[(192 + c) * 2];
        float q = sstat[c * 2 + 1] + sstat[(64 + c) * 2 + 1] + sstat[(128 + c) * 2 + 1] + sstat[(192 + c) * 2 + 1];
        int slot = bid & 7;
        atomicAdd(&ws[WS_SUM + slot * 64 + c], s);
        atomicAdd(&ws[WS_SQ  + slot * 64 + c], q);
    }
}

// ---- kernel 2: finalize BN stats -------------------------------------------
__global__ void gcn_stats(float* ws, const float* __restrict__ gamma,
                          const float* __restrict__ beta) {
    int c = threadIdx.x;
    if (c < COUT_) {
        float s = 0.f, q = 0.f;
        #pragma unroll
        for (int slot = 0; slot < 8; ++slot) {
            s += ws[WS_SUM + slot * 64 + c];
            q += ws[WS_SQ  + slot * 64 + c];
        }
        const float cnt = (float)(N_ * T_ * V_);   // 819200
        float mu  = s / cnt;
        float var = q / cnt - mu * mu;
        float rs  = rsqrtf(var + EPSV);
        float sc  = gamma[c] * rs;
        ws[WS_SCALE + c] = sc;
        ws[WS_SHIFT + c] = fmaf(-mu, sc, beta[c]);
    }
}

// ---- kernel 3: BN apply + residual + ReLU, in-place on d_out ---------------
// block per (n,c): c constant -> no per-iter division, scale/shift hoisted
__global__ __launch_bounds__(256)
void gcn_finish(const float* __restrict__ x, const float* __restrict__ ws,
                float* __restrict__ out) {
    int bid = blockIdx.x;            // n*64 + c
    int c = bid & 63;
    float sc = ws[WS_SCALE + c];
    float sh = ws[WS_SHIFT + c];
    size_t base4 = (size_t)bid * 6400;   // 25600 floats / 4
    const float4* x4 = (const float4*)x;
    float4* o4 = (float4*)out;
    #pragma unroll 2
    for (int it = 0; it < 25; ++it) {
        size_t i = base4 + it * 256 + threadIdx.x;
        float4 a  = o4[i];
        float4 xv = x4[i];
        a.x = fmaxf(0.f, fmaf(a.x, sc, sh) + xv.x);
        a.y = fmaxf(0.f, fmaf(a.y, sc, sh) + xv.y);
        a.z = fmaxf(0.f, fmaf(a.z, sc, sh) + xv.z);
        a.w = fmaxf(0.f, fmaf(a.w, sc, sh) + xv.w);
        o4[i] = a;
    }
}

extern "C" void kernel_launch(void* const* d_in, const int* in_sizes, int n_in,
                              void* d_out, int out_size, void* d_ws, size_t ws_size,
                              hipStream_t stream) {
    (void)in_sizes; (void)n_in; (void)out_size; (void)ws_size;
    const float* x     = (const float*)d_in[0];
    const float* W     = (const float*)d_in[1];
    const float* b     = (const float*)d_in[2];
    const float* A     = (const float*)d_in[3];
    const float* PA    = (const float*)d_in[4];
    const float* gamma = (const float*)d_in[5];
    const float* beta  = (const float*)d_in[6];
    float* out = (float*)d_out;
    float* ws  = (float*)d_ws;

    gcn_prep<<<1, 256, 0, stream>>>(A, PA, b, W, ws);
    gcn_main<<<N_ * (T_ / TC_), 256, 0, stream>>>(x, ws, out);
    gcn_stats<<<1, 64, 0, stream>>>(ws, gamma, beta);
    gcn_finish<<<N_ * COUT_, 256, 0, stream>>>(x, ws, out);
}